// Round 17
// baseline (127.875 us; speedup 1.0000x reference)
//
#include <hip/hip_runtime.h>
#include <hip/hip_bf16.h>
#include <math.h>

#define BB 8
#define TT 256
#define DD 1024
#define HH 512
#define NSPANS 32896   // T*(T+1)/2
#define KK 512
#define NEGV -1e20f
#define NCH 32
#define CHSZ 1028      // NSPANS / NCH
#define NT16 72        // 16x32 span tiles per batch

typedef __attribute__((ext_vector_type(8))) short bf16x8;
typedef __attribute__((ext_vector_type(4))) float f32x4;

__device__ inline unsigned short f2bf(float f) {          // RNE f32->bf16
    unsigned u = __float_as_uint(f);
    return (unsigned short)((u + 0x7FFFu + ((u >> 16) & 1u)) >> 16);
}
__device__ inline float bf2f(unsigned short u) {
    return __uint_as_float(((unsigned)u) << 16);
}
__device__ inline void split3(float v, unsigned short& a, unsigned short& b,
                              unsigned short& c) {
    a = f2bf(v);           float r  = v - bf2f(a);
    b = f2bf(r);           float r2 = r - bf2f(b);
    c = f2bf(r2);
}

// ---------------------------------------------------------------------------
// prep: fused zero + cvt_x + cvt_w(tiled transpose).  (R15/R16, passed)
// ---------------------------------------------------------------------------
__global__ __launch_bounds__(256) void prep(
    const float* __restrict__ X,
    const float* __restrict__ Ws, const float* __restrict__ We,
    unsigned short* __restrict__ x0, unsigned short* __restrict__ x1,
    unsigned short* __restrict__ x2, unsigned short* __restrict__ wt,
    unsigned* __restrict__ zp)
{
    const int blk = blockIdx.x;
    const int tid = threadIdx.x;

    if (blk < 2048) {                               // ---- cvt_x ----
        const int i4 = blk * 256 + tid;
        const float4 v = ((const float4*)X)[i4];
        const float vv[4] = {v.x, v.y, v.z, v.w};
        ushort4 h0, h1, h2;
        unsigned short* p0 = (unsigned short*)&h0;
        unsigned short* p1 = (unsigned short*)&h1;
        unsigned short* p2 = (unsigned short*)&h2;
        #pragma unroll
        for (int j = 0; j < 4; ++j) split3(vv[j], p0[j], p1[j], p2[j]);
        ((ushort4*)x0)[i4] = h0;
        ((ushort4*)x1)[i4] = h1;
        ((ushort4*)x2)[i4] = h2;
    } else if (blk < 3072) {                        // ---- cvt_w tiled ----
        __shared__ float lt[32][33];
        const int blk2 = blk - 2048;
        const int z   = blk2 >> 9;
        const int rem = blk2 & 511;
        const int k0  = (rem >> 4) * 32;
        const int h0  = (rem & 15) * 32;

        const float* Wz = z ? We : Ws;
        {
            const int row = tid >> 3, c4 = tid & 7;
            const float4 v = *(const float4*)&Wz[(k0 + row) * HH + h0 + c4 * 4];
            lt[row][c4*4 + 0] = v.x;
            lt[row][c4*4 + 1] = v.y;
            lt[row][c4*4 + 2] = v.z;
            lt[row][c4*4 + 3] = v.w;
        }
        __syncthreads();
        {
            const int n = h0 + (tid >> 3), kq = tid & 7;
            ushort4 o0, o1, o2;
            unsigned short* q0 = (unsigned short*)&o0;
            unsigned short* q1 = (unsigned short*)&o1;
            unsigned short* q2 = (unsigned short*)&o2;
            #pragma unroll
            for (int u = 0; u < 4; ++u)
                split3(lt[kq*4 + u][tid >> 3], q0[u], q1[u], q2[u]);
            unsigned short* base = wt + (size_t)z * 3 * 524288;
            const int off = n * 1024 + k0 + kq * 4;
            *(ushort4*)&base[0 * 524288 + off] = o0;
            *(ushort4*)&base[1 * 524288 + off] = o1;
            *(ushort4*)&base[2 * 524288 + off] = o2;
        }
    } else {                                        // ---- zero ----
        const int i = (blk - 3072) * 256 + tid;
        for (int k = i; k < 32777; k += 32 * 256) zp[k] = 0u;
    }
}

// ---------------------------------------------------------------------------
// gemm_mfma v6: 64x64 C-tile, IN-BLOCK split-K x2 (512 threads = 2 groups
// x 4 waves; group g owns K-half g, own LDS half, BK=32). LDS 61.4KB ->
// 2 blocks/CU = 16 waves/CU (R16 occupancy) with a SINGLE output array
// (R12 span traffic). Epilogue: LDS pair-reduce + bias (R5/R6 pattern).
// Body = R15 no-spill MFMA core.
// ---------------------------------------------------------------------------
__global__ __launch_bounds__(512) void gemm_mfma(
    const unsigned short* __restrict__ xs,   // [3][2048][1024]
    const unsigned short* __restrict__ wt,   // [2][3][512][1024] (n-major)
    const float* __restrict__ bs, const float* __restrict__ be,
    float* __restrict__ hs, float* __restrict__ he)
{
    const int bid = blockIdx.x;                      // 512
    const int lg  = ((bid & 7) << 6) + (bid >> 3);   // XCD chunks of 64
    const int z   = lg >> 8;
    const int my  = (lg & 255) >> 3, nx = lg & 7;
    const int m0 = my * 64, n0 = nx * 64;

    const unsigned short* __restrict__ W = wt + (size_t)z * 3 * 524288;
    const float* __restrict__ bias = z ? be : bs;
    float* __restrict__ Y = z ? he : hs;

    __shared__ __align__(16) unsigned short la[2][3][64][40];   // [grp][sp]
    __shared__ __align__(16) unsigned short lb[2][3][64][40];

    const int tid = threadIdx.x;
    const int wave8 = tid >> 6;
    const int grp = wave8 >> 2;          // K-group: 0 -> k<512, 1 -> k>=512
    const int wavein = wave8 & 3;
    const int lane = tid & 63;
    const int t = tid & 255;
    const int wm = (wavein >> 1) * 32, wn = (wavein & 1) * 32;
    const int rA = lane & 15, kq = lane >> 4;
    const int kb = grp * 512;

    f32x4 acc[2][2];
    #pragma unroll
    for (int i = 0; i < 2; ++i)
        #pragma unroll
        for (int j = 0; j < 2; ++j) acc[i][j] = (f32x4){0.f, 0.f, 0.f, 0.f};

    const int lrow = t >> 2, lc4 = t & 3;    // per-group: 64 rows x 4 chunks

    for (int kt = 0; kt < 16; ++kt) {
        const int k0 = kb + kt * 32;
        __syncthreads();                 // prev compute done reading LDS
        #pragma unroll
        for (int sp = 0; sp < 3; ++sp) {
            *(int4*)&la[grp][sp][lrow][lc4 * 8] =
                *(const int4*)&xs[(size_t)sp * 2097152 + (m0 + lrow) * 1024 + k0 + lc4 * 8];
            *(int4*)&lb[grp][sp][lrow][lc4 * 8] =
                *(const int4*)&W[(size_t)sp * 524288 + (n0 + lrow) * 1024 + k0 + lc4 * 8];
        }
        __syncthreads();

        bf16x8 af[3][2], bg[3][2];
        #pragma unroll
        for (int sp = 0; sp < 3; ++sp) {
            #pragma unroll
            for (int f = 0; f < 2; ++f) {
                af[sp][f] = *(const bf16x8*)&la[grp][sp][wm + f * 16 + rA][kq * 8];
                bg[sp][f] = *(const bf16x8*)&lb[grp][sp][wn + f * 16 + rA][kq * 8];
            }
        }
        #pragma unroll
        for (int fm = 0; fm < 2; ++fm)
            #pragma unroll
            for (int fn = 0; fn < 2; ++fn) {
                acc[fm][fn] = __builtin_amdgcn_mfma_f32_16x16x32_bf16(
                    af[0][fm], bg[0][fn], acc[fm][fn], 0, 0, 0);
                acc[fm][fn] = __builtin_amdgcn_mfma_f32_16x16x32_bf16(
                    af[0][fm], bg[1][fn], acc[fm][fn], 0, 0, 0);
                acc[fm][fn] = __builtin_amdgcn_mfma_f32_16x16x32_bf16(
                    af[1][fm], bg[0][fn], acc[fm][fn], 0, 0, 0);
                acc[fm][fn] = __builtin_amdgcn_mfma_f32_16x16x32_bf16(
                    af[1][fm], bg[1][fn], acc[fm][fn], 0, 0, 0);
                acc[fm][fn] = __builtin_amdgcn_mfma_f32_16x16x32_bf16(
                    af[0][fm], bg[2][fn], acc[fm][fn], 0, 0, 0);
                acc[fm][fn] = __builtin_amdgcn_mfma_f32_16x16x32_bf16(
                    af[2][fm], bg[0][fn], acc[fm][fn], 0, 0, 0);
            }
    }

    // pair-reduce across K-groups through LDS (reuse la: need 16KB <= 30.7KB)
    __syncthreads();                     // all compute done with LDS
    float* red = (float*)&la[0][0][0][0];
    if (grp == 1) {
        #pragma unroll
        for (int fm = 0; fm < 2; ++fm)
            #pragma unroll
            for (int fn = 0; fn < 2; ++fn)
                *(f32x4*)&red[t * 16 + (fm * 2 + fn) * 4] = acc[fm][fn];
    }
    __syncthreads();
    if (grp == 0) {
        const int col = lane & 15, rq = lane >> 4;
        #pragma unroll
        for (int fm = 0; fm < 2; ++fm)
            #pragma unroll
            for (int fn = 0; fn < 2; ++fn) {
                const int nn = n0 + wn + fn * 16 + col;
                const float bv = bias[nn];
                const f32x4 r4 = *(const f32x4*)&red[t * 16 + (fm * 2 + fn) * 4];
                #pragma unroll
                for (int r = 0; r < 4; ++r) {
                    const int mm = m0 + wm + fm * 16 + rq * 4 + r;
                    Y[mm * HH + nn] = acc[fm][fn][r] + r4[r] + bv;
                }
            }
    }
}

// ---------------------------------------------------------------------------
__device__ inline unsigned f2key(float f) {
    unsigned u = __float_as_uint(f);
    return u ^ ((u & 0x80000000u) ? 0xFFFFFFFFu : 0x80000000u);
}

// ---------------------------------------------------------------------------
// span_scores v4: 16x32 tiles, 128 threads, single hs/he (R12-verified).
// ---------------------------------------------------------------------------
__global__ __launch_bounds__(128) void span_scores(
    const float* __restrict__ hs, const float* __restrict__ he,
    const float* __restrict__ w_score, const float* __restrict__ b_score,
    const int* __restrict__ input_mask, float* __restrict__ scores,
    unsigned* __restrict__ hist12)
{
    const int bx = blockIdx.x;
    const int b = bx / NT16;
    int tI = bx - b * NT16;
    int i = 0, cnt = 8;
    while (tI >= cnt) { tI -= cnt; ++i; cnt = 8 - (i >> 1); }
    const int j = (i >> 1) + tI;
    const int s0 = i * 16, e0 = j * 32;

    __shared__ __align__(16) float shs[16][132];
    __shared__ __align__(16) float she[32][132];
    __shared__ __align__(16) float swc[128];
    __shared__ unsigned lh[2048];

    const int tid = threadIdx.x;
    const float4* hs4 = (const float4*)hs;
    const float4* he4 = (const float4*)he;

    for (int idx = tid; idx < 2048; idx += 128) lh[idx] = 0;

    const int ii = tid >> 4, jj = tid & 15;

    float4 acc[2][2];
    #pragma unroll
    for (int p = 0; p < 2; ++p)
        #pragma unroll
        for (int q = 0; q < 2; ++q) acc[p][q] = make_float4(0.f, 0.f, 0.f, 0.f);

    for (int ck = 0; ck < 4; ++ck) {
        const int kc = ck * 128;
        __syncthreads();
        #pragma unroll
        for (int l = 0; l < 12; ++l) {
            const int idx = l * 128 + tid;
            const int row = idx >> 5, c4 = idx & 31;
            if (row < 16) {
                *(float4*)&shs[row][c4 * 4] =
                    hs4[((b*TT + s0 + row) * HH + kc) / 4 + c4];
            } else {
                *(float4*)&she[row - 16][c4 * 4] =
                    he4[((b*TT + e0 + row - 16) * HH + kc) / 4 + c4];
            }
        }
        if (tid < 32) *(float4*)&swc[tid * 4] =
            ((const float4*)w_score)[kc / 4 + tid];
        __syncthreads();

        #pragma unroll 4
        for (int c4 = 0; c4 < 32; ++c4) {
            const float4 w  = *(const float4*)&swc[c4 * 4];
            const float4 a0 = *(const float4*)&shs[ii][c4 * 4];
            const float4 a1 = *(const float4*)&shs[ii + 8][c4 * 4];
            const float4 v0 = *(const float4*)&she[jj][c4 * 4];
            const float4 v1 = *(const float4*)&she[jj + 16][c4 * 4];
            #pragma unroll
            for (int p = 0; p < 2; ++p) {
                const float4 a = p ? a1 : a0;
                #pragma unroll
                for (int q = 0; q < 2; ++q) {
                    const float4 v = q ? v1 : v0;
                    acc[p][q].x += fmaxf(a.x + v.x, 0.f) * w.x;
                    acc[p][q].y += fmaxf(a.y + v.y, 0.f) * w.y;
                    acc[p][q].z += fmaxf(a.z + v.z, 0.f) * w.z;
                    acc[p][q].w += fmaxf(a.w + v.w, 0.f) * w.w;
                }
            }
        }
    }

    const float bsc = b_score[0];
    #pragma unroll
    for (int p = 0; p < 2; ++p) {
        const int s = s0 + ii + p * 8;
        #pragma unroll
        for (int q = 0; q < 2; ++q) {
            const int e = e0 + jj + q * 16;
            if (e >= s) {
                const float4 a4 = acc[p][q];
                float scv = (a4.x + a4.y) + (a4.z + a4.w) + bsc;
                if (!(input_mask[b*TT + s] && input_mask[b*TT + e])) scv = NEGV;
                scores[b*NSPANS + s*TT - (s*(s-1))/2 + (e - s)] = scv;
                const unsigned bin = f2key(scv) >> 20;
                atomicAdd(&lh[bin >> 1], 1u << ((bin & 1u) * 16));
            }
        }
    }
    __syncthreads();

    for (int idx = tid; idx < 2048; idx += 128) {
        const unsigned w = lh[idx];
        const unsigned lo = w & 0xFFFFu, hi = w >> 16;
        if (lo) atomicAdd(&hist12[b*4096 + 2*idx],     lo);
        if (hi) atomicAdd(&hist12[b*4096 + 2*idx + 1], hi);
    }
}

// ---------------------------------------------------------------------------
__global__ __launch_bounds__(256) void findcompact(
    const float* __restrict__ scores, const unsigned* __restrict__ hist12,
    unsigned* __restrict__ thrInfo,
    unsigned* __restrict__ cand, unsigned* __restrict__ candCnt)
{
    const int b = blockIdx.x >> 5, ch = blockIdx.x & 31;
    const unsigned* h = hist12 + b * 4096;
    const int tid = threadIdx.x;
    const int lane = tid & 63, wave = tid >> 6;

    const int topbin = 4095 - tid * 16;
    unsigned psum = 0;
    #pragma unroll
    for (int j = 0; j < 16; ++j) psum += h[topbin - j];

    unsigned inc = psum;
    #pragma unroll
    for (int off = 1; off < 64; off <<= 1) {
        unsigned v = __shfl_up(inc, off);
        if (lane >= off) inc += v;
    }
    __shared__ unsigned wsum4[4], wpre4[4];
    __shared__ unsigned shp[2];
    if (lane == 63) wsum4[wave] = inc;
    __syncthreads();
    if (tid == 0) { unsigned c = 0; for (int w = 0; w < 4; ++w) { wpre4[w] = c; c += wsum4[w]; } }
    __syncthreads();

    const unsigned before = wpre4[wave] + inc - psum;
    if (before < KK && before + psum >= KK) {
        unsigned cum = before;
        int bin = topbin;
        #pragma unroll
        for (int j = 0; j < 16; ++j) {
            const unsigned c = h[topbin - j];
            if (cum + c >= KK) { bin = topbin - j; break; }
            cum += c;
        }
        shp[0] = (unsigned)bin;
        shp[1] = KK - cum;
        thrInfo[b*4 + 0] = (unsigned)bin;
        thrInfo[b*4 + 1] = KK - cum;
    }
    __syncthreads();
    const unsigned p12 = shp[0];

    const float* sc = scores + b * NSPANS;
    const int base = ch * CHSZ;
    for (int i = base + tid; i < base + CHSZ; i += 256) {
        const unsigned key = f2key(sc[i]);
        if ((key >> 20) == p12) {
            const unsigned pos = atomicAdd(&candCnt[b], 1u);
            cand[b*NSPANS + pos] = key & 0xFFFFFu;
        }
    }
}

// ---------------------------------------------------------------------------
__global__ __launch_bounds__(1024) void refine(
    const unsigned* __restrict__ cand, const unsigned* __restrict__ candCnt,
    const float* __restrict__ scores,
    unsigned* __restrict__ thrInfo, unsigned* __restrict__ chunkBase)
{
    const int b = blockIdx.x;
    const unsigned* cd = cand + b*NSPANS;
    const unsigned n = candCnt[b];
    const unsigned remaining = thrInfo[b*4 + 1];
    const int tid = threadIdx.x;
    const int lane = tid & 63, wave = tid >> 6;

    __shared__ unsigned hist[1024];
    __shared__ unsigned wsum[16], wpre[16];
    __shared__ unsigned sh[2], shT[2];

    hist[tid] = 0;
    __syncthreads();
    for (unsigned i = tid; i < n; i += 1024) atomicAdd(&hist[(cd[i] >> 10) & 1023u], 1u);
    __syncthreads();
    {
        const unsigned psum = hist[1023 - tid];
        unsigned inc = psum;
        #pragma unroll
        for (int off = 1; off < 64; off <<= 1) {
            unsigned v = __shfl_up(inc, off);
            if (lane >= off) inc += v;
        }
        if (lane == 63) wsum[wave] = inc;
        __syncthreads();
        if (tid == 0) { unsigned c = 0; for (int w = 0; w < 16; ++w) { wpre[w] = c; c += wsum[w]; } }
        __syncthreads();
        const unsigned before = wpre[wave] + inc - psum;
        if (before < remaining && before + psum >= remaining && psum > 0) {
            sh[0] = 1023u - (unsigned)tid;
            sh[1] = remaining - before;
        }
        __syncthreads();
    }
    const unsigned b1 = sh[0], rem1 = sh[1];
    __syncthreads();

    hist[tid] = 0;
    __syncthreads();
    for (unsigned i = tid; i < n; i += 1024) {
        const unsigned v = cd[i];
        if (((v >> 10) & 1023u) == b1) atomicAdd(&hist[v & 1023u], 1u);
    }
    __syncthreads();
    {
        const unsigned psum = hist[1023 - tid];
        unsigned inc = psum;
        #pragma unroll
        for (int off = 1; off < 64; off <<= 1) {
            unsigned v = __shfl_up(inc, off);
            if (lane >= off) inc += v;
        }
        if (lane == 63) wsum[wave] = inc;
        __syncthreads();
        if (tid == 0) { unsigned c = 0; for (int w = 0; w < 16; ++w) { wpre[w] = c; c += wsum[w]; } }
        __syncthreads();
        const unsigned before = wpre[wave] + inc - psum;
        if (before < rem1 && before + psum >= rem1 && psum > 0) {
            const unsigned thrv = (thrInfo[b*4 + 0] << 20) | (b1 << 10) | (1023u - (unsigned)tid);
            thrInfo[b*4 + 2] = thrv;
            thrInfo[b*4 + 3] = rem1 - before;
            shT[0] = thrv;
            shT[1] = rem1 - before;
        }
    }
    __syncthreads();
    const unsigned thr = shT[0], ties = shT[1];

    __shared__ unsigned cg[NCH], ce[NCH];
    const float* sc = scores + b*NSPANS;
    #pragma unroll
    for (int q = 0; q < 2; ++q) {
        const int ch = wave*2 + q;
        const int base = ch*CHSZ, end = base + CHSZ;
        unsigned g = 0, e = 0;
        for (int i = base + lane; i < end; i += 64) {
            const unsigned key = f2key(sc[i]);
            g += (key > thr); e += (key == thr);
        }
        #pragma unroll
        for (int off = 32; off; off >>= 1) { g += __shfl_down(g, off); e += __shfl_down(e, off); }
        if (lane == 0) { cg[ch] = g; ce[ch] = e; }
    }
    __syncthreads();

    if (tid == 0) {
        unsigned out = 0, eqp = 0;
        for (int c = 0; c < NCH; ++c) {
            chunkBase[(b*NCH + c)*2 + 0] = out;
            chunkBase[(b*NCH + c)*2 + 1] = eqp;
            const unsigned room = (eqp >= ties) ? 0u : (ties - eqp);
            const unsigned taken = (ce[c] < room) ? ce[c] : room;
            out += cg[c] + taken;
            eqp += ce[c];
        }
    }
}

// ---------------------------------------------------------------------------
__global__ __launch_bounds__(256) void scatter_final(
    const float* __restrict__ scores, const unsigned* __restrict__ thrInfo,
    const unsigned* __restrict__ chunkBase, const int* __restrict__ answer_spans,
    float* __restrict__ chunkLoss, unsigned* __restrict__ ticket,
    float* __restrict__ out)
{
    const int b = blockIdx.x >> 5, ch = blockIdx.x & 31;
    const float* sc = scores + b*NSPANS;
    const unsigned thr = thrInfo[b*4 + 2], ties = thrInfo[b*4 + 3];
    unsigned outPos = chunkBase[(b*NCH + ch)*2 + 0];
    unsigned eqPos  = chunkBase[(b*NCH + ch)*2 + 1];

    const int tid = threadIdx.x, wave = tid >> 6, lane = tid & 63;
    const unsigned long long lmask = (1ull << lane) - 1ull;
    __shared__ unsigned wS[4], wE[4];
    __shared__ int gold[10];
    __shared__ float wLoss[4];
    __shared__ unsigned lastFlag;

    if (tid < 10) {
        const int s0 = answer_spans[b*20 + tid*2];
        const int e0 = answer_spans[b*20 + tid*2 + 1];
        gold[tid] = (s0 >= 0) ? ((2*s0*TT - s0*s0 + s0)/2 + (e0 - s0)) : -1;
    }
    __syncthreads();

    float lsum = 0.f;
    const int base = ch*CHSZ;
    for (int seg = base; seg < base + CHSZ; seg += 256) {
        const int i = seg + tid;
        const bool valid = (i < base + CHSZ);
        const float v = valid ? sc[i] : 0.f;
        const unsigned key = valid ? f2key(v) : 0u;
        const bool g  = valid && key > thr;
        const bool eq = valid && key == thr;

        const unsigned long long meq = __ballot(eq);
        if (lane == 0) wE[wave] = (unsigned)__popcll(meq);
        __syncthreads();

        unsigned eqPre = eqPos;
        for (int w = 0; w < wave; ++w) eqPre += wE[w];
        const unsigned myEqRank = eqPre + (unsigned)__popcll(meq & lmask);
        const bool sel = g || (eq && myEqRank < ties);

        const unsigned long long msel = __ballot(sel);
        if (lane == 0) wS[wave] = (unsigned)__popcll(msel);
        __syncthreads();

        unsigned selPre = outPos;
        for (int w = 0; w < wave; ++w) selPre += wS[w];
        if (sel) {
            const unsigned pos = b*KK + selPre + (unsigned)__popcll(msel & lmask);
            float prob = 0.f;
            if (v > -1e19f) {
                prob = 1.f / (1.f + expf(-v));
                float pred = 0.f;
                #pragma unroll
                for (int gq = 0; gq < 10; ++gq)
                    if (gold[gq] == i) pred = 1.f;
                lsum += fmaxf(v, 0.f) - v*pred + log1pf(expf(-fabsf(v)));
            }
            out[pos] = prob;
        }

        unsigned totS = 0, totE = 0;
        #pragma unroll
        for (int w = 0; w < 4; ++w) { totS += wS[w]; totE += wE[w]; }
        __syncthreads();
        outPos += totS; eqPos += totE;
    }

    #pragma unroll
    for (int off = 32; off; off >>= 1) lsum += __shfl_down(lsum, off);
    if (lane == 0) wLoss[wave] = lsum;
    __syncthreads();
    if (tid == 0) {
        chunkLoss[b*NCH + ch] = (wLoss[0] + wLoss[1]) + (wLoss[2] + wLoss[3]);
        __threadfence();
        lastFlag = atomicAdd(ticket, 1u);
    }
    __syncthreads();

    if (lastFlag == BB*NCH - 1) {
        __threadfence();
        float cl = atomicAdd(&chunkLoss[tid], 0.f);
        #pragma unroll
        for (int off = 32; off; off >>= 1) cl += __shfl_down(cl, off);
        if (lane == 0) wLoss[wave] = cl;
        __syncthreads();
        if (tid == 0)
            out[BB*KK] = (wLoss[0] + wLoss[1]) + (wLoss[2] + wLoss[3]);
    }
}

// ---------------------------------------------------------------------------
extern "C" void kernel_launch(void* const* d_in, const int* in_sizes, int n_in,
                              void* d_out, int out_size, void* d_ws, size_t ws_size,
                              hipStream_t stream)
{
    const float* inputs       = (const float*)d_in[0];
    const int*   input_mask   = (const int*)  d_in[1];
    const int*   answer_spans = (const int*)  d_in[2];
    const float* W_start      = (const float*)d_in[3];
    const float* b_start      = (const float*)d_in[4];
    const float* W_end        = (const float*)d_in[5];
    const float* b_end        = (const float*)d_in[6];
    const float* w_score      = (const float*)d_in[7];
    const float* b_score      = (const float*)d_in[8];
    float* out = (float*)d_out;
    unsigned* ws = (unsigned*)d_ws;

    // word-offset layout (R12-style, single hs/he)
    float*    hs       = (float*)(ws);                 // 1048576
    float*    he       = (float*)(ws + 1048576);       // 1048576
    float*    scores   = (float*)(ws + 2097152);       // 263168
    unsigned* thrInfo  = ws + 2364416;                 // 32
    unsigned* chunkBase= ws + 2364448;                 // 512
    unsigned* hist12   = ws + 2364960;                 // 32768
    unsigned* candCnt  = ws + 2397728;                 // 8
    unsigned* ticket   = ws + 2397736;                 // 1 (zeroed with hist12)
    unsigned short* xs = (unsigned short*)(ws + 2397740);   // 3,145,728 words
    unsigned short* wt = (unsigned short*)(ws + 5543468);   // 1,572,864 words
    float*    chunkLoss= (float*)(ws + 7116332);       // 256
    unsigned* cand     = (unsigned*)hs;                // alias, dead after span

    prep<<<3104, 256, 0, stream>>>(inputs, W_start, W_end,
                                   xs, xs + 2097152, xs + 4194304, wt, hist12);

    gemm_mfma<<<512, 512, 0, stream>>>(xs, wt, b_start, b_end, hs, he);

    span_scores<<<BB*NT16, 128, 0, stream>>>(hs, he, w_score, b_score, input_mask,
                                             scores, hist12);

    findcompact  <<<BB*NCH, 256, 0, stream>>>(scores, hist12, thrInfo, cand, candCnt);
    refine       <<<BB, 1024, 0, stream>>>(cand, candCnt, scores, thrInfo, chunkBase);
    scatter_final<<<BB*NCH, 256, 0, stream>>>(scores, thrInfo, chunkBase,
                                              answer_spans, chunkLoss, ticket, out);
}

// Round 18
// 111.684 us; speedup vs baseline: 1.1450x; 1.1450x over previous
//
#include <hip/hip_runtime.h>
#include <hip/hip_bf16.h>
#include <math.h>

#define BB 8
#define TT 256
#define DD 1024
#define HH 512
#define NSPANS 32896   // T*(T+1)/2
#define KK 512
#define NEGV -1e20f
#define NCH 32
#define CHSZ 1028      // NSPANS / NCH
#define NT32 36        // 8*9/2 span tiles (32x32) per batch

typedef __attribute__((ext_vector_type(8))) short bf16x8;
typedef __attribute__((ext_vector_type(4))) float f32x4;

__device__ inline unsigned short f2bf(float f) {          // RNE f32->bf16
    unsigned u = __float_as_uint(f);
    return (unsigned short)((u + 0x7FFFu + ((u >> 16) & 1u)) >> 16);
}
__device__ inline float bf2f(unsigned short u) {
    return __uint_as_float(((unsigned)u) << 16);
}
__device__ inline void split3(float v, unsigned short& a, unsigned short& b,
                              unsigned short& c) {
    a = f2bf(v);           float r  = v - bf2f(a);
    b = f2bf(r);           float r2 = r - bf2f(b);
    c = f2bf(r2);
}

// ---------------------------------------------------------------------------
// prep: fused zero + cvt_x + cvt_w (tiled transpose, coalesced both sides).
// blocks [0,2048)    : cvt_x
// blocks [2048,3072) : cvt_w
// blocks [3072,3104) : zero hist12+candCnt+ticket (32777 words)
// ---------------------------------------------------------------------------
__global__ __launch_bounds__(256) void prep(
    const float* __restrict__ X,
    const float* __restrict__ Ws, const float* __restrict__ We,
    unsigned short* __restrict__ x0, unsigned short* __restrict__ x1,
    unsigned short* __restrict__ x2, unsigned short* __restrict__ wt,
    unsigned* __restrict__ zp)
{
    const int blk = blockIdx.x;
    const int tid = threadIdx.x;

    if (blk < 2048) {                               // ---- cvt_x ----
        const int i4 = blk * 256 + tid;
        const float4 v = ((const float4*)X)[i4];
        const float vv[4] = {v.x, v.y, v.z, v.w};
        ushort4 h0, h1, h2;
        unsigned short* p0 = (unsigned short*)&h0;
        unsigned short* p1 = (unsigned short*)&h1;
        unsigned short* p2 = (unsigned short*)&h2;
        #pragma unroll
        for (int j = 0; j < 4; ++j) split3(vv[j], p0[j], p1[j], p2[j]);
        ((ushort4*)x0)[i4] = h0;
        ((ushort4*)x1)[i4] = h1;
        ((ushort4*)x2)[i4] = h2;
    } else if (blk < 3072) {                        // ---- cvt_w tiled ----
        __shared__ float lt[32][33];
        const int blk2 = blk - 2048;
        const int z   = blk2 >> 9;
        const int rem = blk2 & 511;
        const int k0  = (rem >> 4) * 32;
        const int h0  = (rem & 15) * 32;

        const float* Wz = z ? We : Ws;
        {
            const int row = tid >> 3, c4 = tid & 7;
            const float4 v = *(const float4*)&Wz[(k0 + row) * HH + h0 + c4 * 4];
            lt[row][c4*4 + 0] = v.x;
            lt[row][c4*4 + 1] = v.y;
            lt[row][c4*4 + 2] = v.z;
            lt[row][c4*4 + 3] = v.w;
        }
        __syncthreads();
        {
            const int n = h0 + (tid >> 3), kq = tid & 7;
            ushort4 o0, o1, o2;
            unsigned short* q0 = (unsigned short*)&o0;
            unsigned short* q1 = (unsigned short*)&o1;
            unsigned short* q2 = (unsigned short*)&o2;
            #pragma unroll
            for (int u = 0; u < 4; ++u)
                split3(lt[kq*4 + u][tid >> 3], q0[u], q1[u], q2[u]);
            unsigned short* base = wt + (size_t)z * 3 * 524288;
            const int off = n * 1024 + k0 + kq * 4;
            *(ushort4*)&base[0 * 524288 + off] = o0;
            *(ushort4*)&base[1 * 524288 + off] = o1;
            *(ushort4*)&base[2 * 524288 + off] = o2;
        }
    } else {                                        // ---- zero ----
        const int i = (blk - 3072) * 256 + tid;
        for (int k = i; k < 32777; k += 32 * 256) zp[k] = 0u;
    }
}

// ---------------------------------------------------------------------------
// gemm_mfma (R8/R11 best build): 64x64 C-tile, BK=64, 4 waves x 32x32,
// 512 blocks x 256 thr, XCD swizzle. In the 114.77 us build.
// ---------------------------------------------------------------------------
__global__ __launch_bounds__(256) void gemm_mfma(
    const unsigned short* __restrict__ xs,   // [3][2048][1024]
    const unsigned short* __restrict__ wt,   // [2][3][512][1024] (n-major)
    const float* __restrict__ bs, const float* __restrict__ be,
    float* __restrict__ hs, float* __restrict__ he)
{
    const int bid = blockIdx.x;
    const int lg  = ((bid & 7) << 6) + (bid >> 3);   // XCD-chunked swizzle
    const int z   = lg >> 8;
    const int my  = (lg & 255) >> 3, nx = lg & 7;
    const int m0 = my * 64, n0 = nx * 64;

    const unsigned short* __restrict__ W = wt + (size_t)z * 3 * 524288;
    const float* __restrict__ bias = z ? be : bs;
    float* __restrict__ Y = z ? he : hs;

    __shared__ __align__(16) unsigned short la[3][64][72];
    __shared__ __align__(16) unsigned short lb[3][64][72];

    const int tid = threadIdx.x;
    const int wave = tid >> 6, lane = tid & 63;
    const int wm = (wave >> 1) * 32, wn = (wave & 1) * 32;

    f32x4 acc[2][2];
    #pragma unroll
    for (int i = 0; i < 2; ++i)
        #pragma unroll
        for (int j = 0; j < 2; ++j) acc[i][j] = (f32x4){0.f, 0.f, 0.f, 0.f};

    const int rA = lane & 15;
    const int kq = lane >> 4;

    for (int kt = 0; kt < 16; ++kt) {
        const int k0 = kt * 64;
        __syncthreads();
        #pragma unroll
        for (int sp = 0; sp < 3; ++sp) {
            #pragma unroll
            for (int it = 0; it < 2; ++it) {
                const int idx = it * 256 + tid;
                const int row = idx >> 3, c8 = idx & 7;
                *(int4*)&la[sp][row][c8 * 8] =
                    *(const int4*)&xs[(size_t)sp * 2097152 + (m0 + row) * 1024 + k0 + c8 * 8];
                *(int4*)&lb[sp][row][c8 * 8] =
                    *(const int4*)&W[(size_t)sp * 524288 + (n0 + row) * 1024 + k0 + c8 * 8];
            }
        }
        __syncthreads();

        #pragma unroll
        for (int s = 0; s < 2; ++s) {
            const int kl = s * 32 + kq * 8;
            bf16x8 af[3][2], bg[3][2];
            #pragma unroll
            for (int sp = 0; sp < 3; ++sp) {
                #pragma unroll
                for (int f = 0; f < 2; ++f) {
                    af[sp][f] = *(const bf16x8*)&la[sp][wm + f * 16 + rA][kl];
                    bg[sp][f] = *(const bf16x8*)&lb[sp][wn + f * 16 + rA][kl];
                }
            }
            #pragma unroll
            for (int fm = 0; fm < 2; ++fm)
                #pragma unroll
                for (int fn = 0; fn < 2; ++fn) {
                    acc[fm][fn] = __builtin_amdgcn_mfma_f32_16x16x32_bf16(
                        af[0][fm], bg[0][fn], acc[fm][fn], 0, 0, 0);
                    acc[fm][fn] = __builtin_amdgcn_mfma_f32_16x16x32_bf16(
                        af[0][fm], bg[1][fn], acc[fm][fn], 0, 0, 0);
                    acc[fm][fn] = __builtin_amdgcn_mfma_f32_16x16x32_bf16(
                        af[1][fm], bg[0][fn], acc[fm][fn], 0, 0, 0);
                    acc[fm][fn] = __builtin_amdgcn_mfma_f32_16x16x32_bf16(
                        af[1][fm], bg[1][fn], acc[fm][fn], 0, 0, 0);
                    acc[fm][fn] = __builtin_amdgcn_mfma_f32_16x16x32_bf16(
                        af[0][fm], bg[2][fn], acc[fm][fn], 0, 0, 0);
                    acc[fm][fn] = __builtin_amdgcn_mfma_f32_16x16x32_bf16(
                        af[2][fm], bg[0][fn], acc[fm][fn], 0, 0, 0);
                }
        }
    }

    const int col = lane & 15, rq = lane >> 4;
    #pragma unroll
    for (int fm = 0; fm < 2; ++fm)
        #pragma unroll
        for (int fn = 0; fn < 2; ++fn) {
            const int nn = n0 + wn + fn * 16 + col;
            const float bv = bias[nn];
            #pragma unroll
            for (int r = 0; r < 4; ++r) {
                const int mm = m0 + wm + fm * 16 + rq * 4 + r;
                Y[mm * HH + nn] = acc[fm][fn][r] + bv;
            }
        }
}

// ---------------------------------------------------------------------------
__device__ inline unsigned f2key(float f) {
    unsigned u = __float_as_uint(f);
    return u ^ ((u & 0x80000000u) ? 0xFFFFFFFFu : 0x80000000u);
}

// ---------------------------------------------------------------------------
// span_scores v3 (from the 114.77 build): 32x32 tiles, 256 thr, 2x2 reg
// blocking, k-chunked LDS, fused u16-packed 12-bit histogram.
// ---------------------------------------------------------------------------
__global__ __launch_bounds__(256) void span_scores(
    const float* __restrict__ hs, const float* __restrict__ he,
    const float* __restrict__ w_score, const float* __restrict__ b_score,
    const int* __restrict__ input_mask, float* __restrict__ scores,
    unsigned* __restrict__ hist12)
{
    const int bx = blockIdx.x;
    const int b = bx / NT32;
    int tI = bx - b * NT32;
    int i = 0, cum = 0;
    while (tI >= cum + (8 - i)) { cum += 8 - i; ++i; }
    const int j = i + (tI - cum);
    const int s0 = i * 32, e0 = j * 32;

    __shared__ __align__(16) float shs[32][132];
    __shared__ __align__(16) float she[32][132];
    __shared__ __align__(16) float swc[128];
    __shared__ unsigned lh[2048];    // 4096 bins packed 2 x u16

    const int tid = threadIdx.x;
    const float4* hs4 = (const float4*)hs;
    const float4* he4 = (const float4*)he;

    for (int idx = tid; idx < 2048; idx += 256) lh[idx] = 0;

    const int ii = tid >> 4, jj = tid & 15;

    float4 acc[2][2];
    #pragma unroll
    for (int p = 0; p < 2; ++p)
        #pragma unroll
        for (int q = 0; q < 2; ++q) acc[p][q] = make_float4(0.f, 0.f, 0.f, 0.f);

    for (int ck = 0; ck < 4; ++ck) {
        const int kc = ck * 128;       // chunk base (floats)
        __syncthreads();               // prev-iter reads done
        #pragma unroll
        for (int l = 0; l < 4; ++l) {
            const int idx = l * 256 + tid;       // 0..1023
            const int row = idx >> 5, c4 = idx & 31;
            *(float4*)&shs[row][c4 * 4] =
                hs4[((b*TT + s0 + row) * HH + kc) / 4 + c4];
            *(float4*)&she[row][c4 * 4] =
                he4[((b*TT + e0 + row) * HH + kc) / 4 + c4];
        }
        if (tid < 32) *(float4*)&swc[tid * 4] =
            ((const float4*)w_score)[kc / 4 + tid];
        __syncthreads();

        #pragma unroll 4
        for (int c4 = 0; c4 < 32; ++c4) {
            const float4 w  = *(const float4*)&swc[c4 * 4];
            const float4 a0 = *(const float4*)&shs[ii][c4 * 4];
            const float4 a1 = *(const float4*)&shs[ii + 16][c4 * 4];
            const float4 v0 = *(const float4*)&she[jj][c4 * 4];
            const float4 v1 = *(const float4*)&she[jj + 16][c4 * 4];
            #pragma unroll
            for (int p = 0; p < 2; ++p) {
                const float4 a = p ? a1 : a0;
                #pragma unroll
                for (int q = 0; q < 2; ++q) {
                    const float4 v = q ? v1 : v0;
                    acc[p][q].x += fmaxf(a.x + v.x, 0.f) * w.x;
                    acc[p][q].y += fmaxf(a.y + v.y, 0.f) * w.y;
                    acc[p][q].z += fmaxf(a.z + v.z, 0.f) * w.z;
                    acc[p][q].w += fmaxf(a.w + v.w, 0.f) * w.w;
                }
            }
        }
    }

    const float bsc = b_score[0];
    #pragma unroll
    for (int p = 0; p < 2; ++p) {
        const int s = s0 + ii + p * 16;
        #pragma unroll
        for (int q = 0; q < 2; ++q) {
            const int e = e0 + jj + q * 16;
            if (e >= s) {
                const float4 a4 = acc[p][q];
                float scv = (a4.x + a4.y) + (a4.z + a4.w) + bsc;
                if (!(input_mask[b*TT + s] && input_mask[b*TT + e])) scv = NEGV;
                scores[b*NSPANS + s*TT - (s*(s-1))/2 + (e - s)] = scv;
                const unsigned bin = f2key(scv) >> 20;
                atomicAdd(&lh[bin >> 1], 1u << ((bin & 1u) * 16));
            }
        }
    }
    __syncthreads();

    for (int idx = tid; idx < 2048; idx += 256) {
        const unsigned w = lh[idx];
        const unsigned lo = w & 0xFFFFu, hi = w >> 16;
        if (lo) atomicAdd(&hist12[b*4096 + 2*idx],     lo);
        if (hi) atomicAdd(&hist12[b*4096 + 2*idx + 1], hi);
    }
}

// ---------------------------------------------------------------------------
__global__ __launch_bounds__(256) void findcompact(
    const float* __restrict__ scores, const unsigned* __restrict__ hist12,
    unsigned* __restrict__ thrInfo,
    unsigned* __restrict__ cand, unsigned* __restrict__ candCnt)
{
    const int b = blockIdx.x >> 5, ch = blockIdx.x & 31;
    const unsigned* h = hist12 + b * 4096;
    const int tid = threadIdx.x;
    const int lane = tid & 63, wave = tid >> 6;

    const int topbin = 4095 - tid * 16;
    unsigned psum = 0;
    #pragma unroll
    for (int j = 0; j < 16; ++j) psum += h[topbin - j];

    unsigned inc = psum;
    #pragma unroll
    for (int off = 1; off < 64; off <<= 1) {
        unsigned v = __shfl_up(inc, off);
        if (lane >= off) inc += v;
    }
    __shared__ unsigned wsum4[4], wpre4[4];
    __shared__ unsigned shp[2];
    if (lane == 63) wsum4[wave] = inc;
    __syncthreads();
    if (tid == 0) { unsigned c = 0; for (int w = 0; w < 4; ++w) { wpre4[w] = c; c += wsum4[w]; } }
    __syncthreads();

    const unsigned before = wpre4[wave] + inc - psum;
    if (before < KK && before + psum >= KK) {
        unsigned cum = before;
        int bin = topbin;
        #pragma unroll
        for (int j = 0; j < 16; ++j) {
            const unsigned c = h[topbin - j];
            if (cum + c >= KK) { bin = topbin - j; break; }
            cum += c;
        }
        shp[0] = (unsigned)bin;
        shp[1] = KK - cum;
        thrInfo[b*4 + 0] = (unsigned)bin;
        thrInfo[b*4 + 1] = KK - cum;
    }
    __syncthreads();
    const unsigned p12 = shp[0];

    const float* sc = scores + b * NSPANS;
    const int base = ch * CHSZ;
    for (int i = base + tid; i < base + CHSZ; i += 256) {
        const unsigned key = f2key(sc[i]);
        if ((key >> 20) == p12) {
            const unsigned pos = atomicAdd(&candCnt[b], 1u);
            cand[b*NSPANS + pos] = key & 0xFFFFFu;
        }
    }
}

// ---------------------------------------------------------------------------
__global__ __launch_bounds__(1024) void refine(
    const unsigned* __restrict__ cand, const unsigned* __restrict__ candCnt,
    const float* __restrict__ scores,
    unsigned* __restrict__ thrInfo, unsigned* __restrict__ chunkBase)
{
    const int b = blockIdx.x;
    const unsigned* cd = cand + b*NSPANS;
    const unsigned n = candCnt[b];
    const unsigned remaining = thrInfo[b*4 + 1];
    const int tid = threadIdx.x;
    const int lane = tid & 63, wave = tid >> 6;

    __shared__ unsigned hist[1024];
    __shared__ unsigned wsum[16], wpre[16];
    __shared__ unsigned sh[2], shT[2];

    hist[tid] = 0;
    __syncthreads();
    for (unsigned i = tid; i < n; i += 1024) atomicAdd(&hist[(cd[i] >> 10) & 1023u], 1u);
    __syncthreads();
    {
        const unsigned psum = hist[1023 - tid];
        unsigned inc = psum;
        #pragma unroll
        for (int off = 1; off < 64; off <<= 1) {
            unsigned v = __shfl_up(inc, off);
            if (lane >= off) inc += v;
        }
        if (lane == 63) wsum[wave] = inc;
        __syncthreads();
        if (tid == 0) { unsigned c = 0; for (int w = 0; w < 16; ++w) { wpre[w] = c; c += wsum[w]; } }
        __syncthreads();
        const unsigned before = wpre[wave] + inc - psum;
        if (before < remaining && before + psum >= remaining && psum > 0) {
            sh[0] = 1023u - (unsigned)tid;
            sh[1] = remaining - before;
        }
        __syncthreads();
    }
    const unsigned b1 = sh[0], rem1 = sh[1];
    __syncthreads();

    hist[tid] = 0;
    __syncthreads();
    for (unsigned i = tid; i < n; i += 1024) {
        const unsigned v = cd[i];
        if (((v >> 10) & 1023u) == b1) atomicAdd(&hist[v & 1023u], 1u);
    }
    __syncthreads();
    {
        const unsigned psum = hist[1023 - tid];
        unsigned inc = psum;
        #pragma unroll
        for (int off = 1; off < 64; off <<= 1) {
            unsigned v = __shfl_up(inc, off);
            if (lane >= off) inc += v;
        }
        if (lane == 63) wsum[wave] = inc;
        __syncthreads();
        if (tid == 0) { unsigned c = 0; for (int w = 0; w < 16; ++w) { wpre[w] = c; c += wsum[w]; } }
        __syncthreads();
        const unsigned before = wpre[wave] + inc - psum;
        if (before < rem1 && before + psum >= rem1 && psum > 0) {
            const unsigned thrv = (thrInfo[b*4 + 0] << 20) | (b1 << 10) | (1023u - (unsigned)tid);
            thrInfo[b*4 + 2] = thrv;
            thrInfo[b*4 + 3] = rem1 - before;
            shT[0] = thrv;
            shT[1] = rem1 - before;
        }
    }
    __syncthreads();
    const unsigned thr = shT[0], ties = shT[1];

    __shared__ unsigned cg[NCH], ce[NCH];
    const float* sc = scores + b*NSPANS;
    #pragma unroll
    for (int q = 0; q < 2; ++q) {
        const int ch = wave*2 + q;
        const int base = ch*CHSZ, end = base + CHSZ;
        unsigned g = 0, e = 0;
        for (int i = base + lane; i < end; i += 64) {
            const unsigned key = f2key(sc[i]);
            g += (key > thr); e += (key == thr);
        }
        #pragma unroll
        for (int off = 32; off; off >>= 1) { g += __shfl_down(g, off); e += __shfl_down(e, off); }
        if (lane == 0) { cg[ch] = g; ce[ch] = e; }
    }
    __syncthreads();

    if (tid == 0) {
        unsigned out = 0, eqp = 0;
        for (int c = 0; c < NCH; ++c) {
            chunkBase[(b*NCH + c)*2 + 0] = out;
            chunkBase[(b*NCH + c)*2 + 1] = eqp;
            const unsigned room = (eqp >= ties) ? 0u : (ties - eqp);
            const unsigned taken = (ce[c] < room) ? ce[c] : room;
            out += cg[c] + taken;
            eqp += ce[c];
        }
    }
}

// ---------------------------------------------------------------------------
__global__ __launch_bounds__(256) void scatter_final(
    const float* __restrict__ scores, const unsigned* __restrict__ thrInfo,
    const unsigned* __restrict__ chunkBase, const int* __restrict__ answer_spans,
    float* __restrict__ chunkLoss, unsigned* __restrict__ ticket,
    float* __restrict__ out)
{
    const int b = blockIdx.x >> 5, ch = blockIdx.x & 31;
    const float* sc = scores + b*NSPANS;
    const unsigned thr = thrInfo[b*4 + 2], ties = thrInfo[b*4 + 3];
    unsigned outPos = chunkBase[(b*NCH + ch)*2 + 0];
    unsigned eqPos  = chunkBase[(b*NCH + ch)*2 + 1];

    const int tid = threadIdx.x, wave = tid >> 6, lane = tid & 63;
    const unsigned long long lmask = (1ull << lane) - 1ull;
    __shared__ unsigned wS[4], wE[4];
    __shared__ int gold[10];
    __shared__ float wLoss[4];
    __shared__ unsigned lastFlag;

    if (tid < 10) {
        const int s0 = answer_spans[b*20 + tid*2];
        const int e0 = answer_spans[b*20 + tid*2 + 1];
        gold[tid] = (s0 >= 0) ? ((2*s0*TT - s0*s0 + s0)/2 + (e0 - s0)) : -1;
    }
    __syncthreads();

    float lsum = 0.f;
    const int base = ch*CHSZ;
    for (int seg = base; seg < base + CHSZ; seg += 256) {
        const int i = seg + tid;
        const bool valid = (i < base + CHSZ);
        const float v = valid ? sc[i] : 0.f;
        const unsigned key = valid ? f2key(v) : 0u;
        const bool g  = valid && key > thr;
        const bool eq = valid && key == thr;

        const unsigned long long meq = __ballot(eq);
        if (lane == 0) wE[wave] = (unsigned)__popcll(meq);
        __syncthreads();

        unsigned eqPre = eqPos;
        for (int w = 0; w < wave; ++w) eqPre += wE[w];
        const unsigned myEqRank = eqPre + (unsigned)__popcll(meq & lmask);
        const bool sel = g || (eq && myEqRank < ties);

        const unsigned long long msel = __ballot(sel);
        if (lane == 0) wS[wave] = (unsigned)__popcll(msel);
        __syncthreads();

        unsigned selPre = outPos;
        for (int w = 0; w < wave; ++w) selPre += wS[w];
        if (sel) {
            const unsigned pos = b*KK + selPre + (unsigned)__popcll(msel & lmask);
            float prob = 0.f;
            if (v > -1e19f) {
                prob = 1.f / (1.f + expf(-v));
                float pred = 0.f;
                #pragma unroll
                for (int gq = 0; gq < 10; ++gq)
                    if (gold[gq] == i) pred = 1.f;
                lsum += fmaxf(v, 0.f) - v*pred + log1pf(expf(-fabsf(v)));
            }
            out[pos] = prob;
        }

        unsigned totS = 0, totE = 0;
        #pragma unroll
        for (int w = 0; w < 4; ++w) { totS += wS[w]; totE += wE[w]; }
        __syncthreads();
        outPos += totS; eqPos += totE;
    }

    #pragma unroll
    for (int off = 32; off; off >>= 1) lsum += __shfl_down(lsum, off);
    if (lane == 0) wLoss[wave] = lsum;
    __syncthreads();
    if (tid == 0) {
        chunkLoss[b*NCH + ch] = (wLoss[0] + wLoss[1]) + (wLoss[2] + wLoss[3]);
        __threadfence();
        lastFlag = atomicAdd(ticket, 1u);
    }
    __syncthreads();

    if (lastFlag == BB*NCH - 1) {
        __threadfence();
        float cl = atomicAdd(&chunkLoss[tid], 0.f);
        #pragma unroll
        for (int off = 32; off; off >>= 1) cl += __shfl_down(cl, off);
        if (lane == 0) wLoss[wave] = cl;
        __syncthreads();
        if (tid == 0)
            out[BB*KK] = (wLoss[0] + wLoss[1]) + (wLoss[2] + wLoss[3]);
    }
}

// ---------------------------------------------------------------------------
extern "C" void kernel_launch(void* const* d_in, const int* in_sizes, int n_in,
                              void* d_out, int out_size, void* d_ws, size_t ws_size,
                              hipStream_t stream)
{
    const float* inputs       = (const float*)d_in[0];
    const int*   input_mask   = (const int*)  d_in[1];
    const int*   answer_spans = (const int*)  d_in[2];
    const float* W_start      = (const float*)d_in[3];
    const float* b_start      = (const float*)d_in[4];
    const float* W_end        = (const float*)d_in[5];
    const float* b_end        = (const float*)d_in[6];
    const float* w_score      = (const float*)d_in[7];
    const float* b_score      = (const float*)d_in[8];
    float* out = (float*)d_out;
    unsigned* ws = (unsigned*)d_ws;

    // word-offset layout (single hs/he)
    float*    hs       = (float*)(ws);                 // 1048576
    float*    he       = (float*)(ws + 1048576);       // 1048576
    float*    scores   = (float*)(ws + 2097152);       // 263168
    unsigned* thrInfo  = ws + 2364416;                 // 32
    unsigned* chunkBase= ws + 2364448;                 // 512
    unsigned* hist12   = ws + 2364960;                 // 32768
    unsigned* candCnt  = ws + 2397728;                 // 8
    unsigned* ticket   = ws + 2397736;                 // 1 (zeroed with hist12)
    unsigned short* xs = (unsigned short*)(ws + 2397740);   // 3,145,728 words
    unsigned short* wt = (unsigned short*)(ws + 5543468);   // 1,572,864 words
    float*    chunkLoss= (float*)(ws + 7116332);       // 256
    unsigned* cand     = (unsigned*)hs;                // alias, hs dead after span

    prep<<<3104, 256, 0, stream>>>(inputs, W_start, W_end,
                                   xs, xs + 2097152, xs + 4194304, wt, hist12);

    gemm_mfma<<<512, 256, 0, stream>>>(xs, wt, b_start, b_end, hs, he);

    span_scores<<<BB*NT32, 256, 0, stream>>>(hs, he, w_score, b_score, input_mask,
                                             scores, hist12);

    findcompact  <<<BB*NCH, 256, 0, stream>>>(scores, hist12, thrInfo, cand, candCnt);
    refine       <<<BB, 1024, 0, stream>>>(cand, candCnt, scores, thrInfo, chunkBase);
    scatter_final<<<BB*NCH, 256, 0, stream>>>(scores, thrInfo, chunkBase,
                                              answer_spans, chunkLoss, ticket, out);
}